// Round 11
// baseline (8194.752 us; speedup 1.0000x reference)
//
#include <hip/hip_runtime.h>
#include <stdint.h>

// ---------------- geometry ----------------
// B=1024, T=512, I=64, H=256, gates 4H=1024 (i,f,g,o)
// R11: 128 blocks x 512 threads (8 waves = 2 waves/SIMD on 128 CUs).
//   bid = s*8 + gp  (s = slice 0..15, gp = 0..7)
//   Each block hosts TWO independent groups sharing its LDS weight slice:
//     grp 0 = waves 0-3 -> group g = gp*2     (batch rows [g*64, +64))
//     grp 1 = waves 4-7 -> group g = gp*2+1
//   Wave wvg (0..3) of a group owns rows [g*64+wvg*16, +16)  (= R10 wave work).
//   2 waves/SIMD: when one group's waves stall on vmcnt/poll, the other
//   group's co-resident waves issue MFMA/LDS -> stalls overlap compute.
// slice s owns h-columns [s*16,+16) of BOTH layers.
// Exchange: L3-coherent data (sc0 sc1) + per-(group,slice) FLAG words (plain
// sc0sc1 stores, no RMW) - R10-proven. NO block-wide sync in the loop;
// producer-side intra-group ack = LDS last-arriver atomic (monotonic).
// Pipelined schedule (R9/R10-validated): super-step t computes L0(t) and
// L1(t-1); flags0 = h0 (critical path), flags1 = h1 (shadow); h1(t-1) loads
// fly across the loop edge; W_hh1 MFMAs run under the h0 load flight.
// Precision (R7+): weights f16, h hi/lo f16 pair (exact), x hi/lo f16,
// f32 MFMA accum, c state f32 in registers.
// vmcnt ledger per wave per iteration (ALL in-loop vmem inline asm; no
// runtime-indexed local arrays -> no scratch; DS atomics are lgkmcnt):
//   ops 1-16: h0(t-1) loads   ops 17-20: x(t+1) loads
//   VM_WAIT(4)  -> h0 in regs (x may linger)
//   ops 21-28: h0(t) stores
//   VM_WAIT(0)  -> x in regs + h0 stores acked; LDS arrive; last wave -> flag0
//   ops: h1(t-1) stores (8, t>0) [+ flag0 store in flight]
//   VM_WAIT(0)  -> h1 stores (+flag0) acked; LDS arrive; last wave -> flag1
//   poll1 (flags1 >= t+1, probes drain vmcnt to 0)
//   issue h1(t-1) loads (16) -> drained by next poll0's first probe.

#define T_STEPS 512
#define NC0 10
#define NC1 16
#define WSLICE_ELEMS (4*(NC0+NC1)*512)   // 53248 f16 elems = 104KB
#define L1_OFF (4*NC0*512)               // 20480
#define HN (1024*256)                    // elems per h array
// h layout: h0hi[p]=hbase+p*HN, h0lo[p]=+2HN+p*HN, h1hi[p]=+4HN+p*HN, h1lo[p]=+6HN+p*HN

typedef __attribute__((ext_vector_type(8))) short short8;
typedef __attribute__((ext_vector_type(4))) float floatx4;
typedef __attribute__((ext_vector_type(4))) int   intx4;
typedef _Float16 half8 __attribute__((ext_vector_type(8)));

#define MFMA16(A,B,C) __builtin_amdgcn_mfma_f32_16x16x32_f16( \
    __builtin_bit_cast(half8,(A)), __builtin_bit_cast(half8,(B)), (C), 0, 0, 0)

__device__ __forceinline__ float sigm(float x){
  return __builtin_amdgcn_rcpf(1.0f + __builtin_amdgcn_exp2f(-1.44269504f*x));
}
__device__ __forceinline__ float tanhf_(float x){
  return 1.0f - 2.0f*__builtin_amdgcn_rcpf(1.0f + __builtin_amdgcn_exp2f(2.88539008f*x));
}
__device__ __forceinline__ floatx4 splat4(float v){ return (floatx4){v,v,v,v}; }
__device__ __forceinline__ int imin2(int a, int b){ return a < b ? a : b; }

__device__ __forceinline__ void cvt8h(const floatx4& v0, const floatx4& v1, short8& hi, short8& lo){
  #pragma unroll
  for (int j = 0; j < 8; ++j){
    float f = (j < 4) ? v0[j] : v1[j-4];
    _Float16 h = (_Float16)f;
    _Float16 l = (_Float16)(f - (float)h);
    hi[j] = (short)__builtin_bit_cast(uint16_t, h);
    lo[j] = (short)__builtin_bit_cast(uint16_t, l);
  }
}

// ---- L3-coherent vmem (sc0 sc1) ----
__device__ __forceinline__ short8 load_coh16(const uint16_t* p){
  short8 r;
  asm volatile("global_load_dwordx4 %0, %1, off sc0 sc1" : "=v"(r) : "v"(p));
  return r;
}
__device__ __forceinline__ void store_coh2(uint16_t* p, uint32_t v){
  asm volatile("global_store_short %0, %1, off sc0 sc1" :: "v"(p), "v"(v) : "memory");
}
__device__ __forceinline__ floatx4 load_g16f(const float* p){
  floatx4 r;
  asm volatile("global_load_dwordx4 %0, %1, off" : "=v"(r) : "v"(p));
  return r;
}
__device__ __forceinline__ void flag_store(int* p, int v){
  asm volatile("global_store_dword %0, %1, off sc0 sc1" :: "v"(p), "v"(v) : "memory");
}
__device__ __forceinline__ intx4 load_flags4(const int* p){
  intx4 r;
  asm volatile("global_load_dwordx4 %0, %1, off sc0 sc1" : "=v"(r) : "v"(p));
  return r;
}
#define VM_WAIT(N) do{ asm volatile("s_waitcnt vmcnt(" #N ")" ::: "memory"); \
                       __builtin_amdgcn_sched_barrier(0); }while(0)

// Poll 16 contiguous flag words until min >= target (wave-uniform broadcast
// loads). Every probe drains vmcnt(0) -> in-flight loads from the previous
// phase are always drained on exit.
__device__ __forceinline__ void poll_flags(const int* f, int target){
  int spins = 0;
  for(;;){
    intx4 a = load_flags4(f);
    intx4 b = load_flags4(f + 4);
    intx4 c = load_flags4(f + 8);
    intx4 d = load_flags4(f + 12);
    VM_WAIT(0);
    int m = imin2(imin2(a[0],a[1]), imin2(a[2],a[3]));
    m = imin2(m, imin2(imin2(b[0],b[1]), imin2(b[2],b[3])));
    m = imin2(m, imin2(imin2(c[0],c[1]), imin2(c[2],c[3])));
    m = imin2(m, imin2(imin2(d[0],d[1]), imin2(d[2],d[3])));
    if (m >= target) break;
    if (++spins > (1<<20)) break;      // bounded: fail loud, never hang
    __builtin_amdgcn_s_sleep(1);
  }
  __builtin_amdgcn_sched_barrier(0);   // keep consumers below the final wait
}

// ---------------- prep: gather weights into per-slice B-fragment images (f16) ----------------
extern "C" __global__ void prep_weights(const float* __restrict__ wih0, const float* __restrict__ whh0,
                                        const float* __restrict__ wih1, const float* __restrict__ whh1,
                                        uint16_t* __restrict__ wfrag)
{
  int idx = blockIdx.x*256 + threadIdx.x;     // exactly 16*WSLICE_ELEMS threads
  int s  = idx / WSLICE_ELEMS;
  int r  = idx - s*WSLICE_ELEMS;
  int layer = (r >= L1_OFF) ? 1 : 0;
  int rr = layer ? (r - L1_OFF) : r;
  int nc = layer ? NC1 : NC0;
  int n  = rr / (nc*512);
  int c  = (rr / 512) % nc;
  int l  = (rr >> 3) & 63;
  int j  = rr & 7;
  int k  = c*32 + ((l >> 4) << 3) + j;        // B frag: lane l holds col=l&15, k=8*(l>>4)+j
  int grow = n*256 + s*16 + (l & 15);
  float v;
  if (!layer) v = (k < 64)  ? wih0[grow*64  + k] : whh0[grow*256 + (k - 64)];
  else        v = (k < 256) ? wih1[grow*256 + k] : whh1[grow*256 + (k - 256)];
  wfrag[idx] = __builtin_bit_cast(uint16_t, (_Float16)v);
}

extern "C" __global__ void prep_bias(const float* __restrict__ bih0, const float* __restrict__ bhh0,
                                     const float* __restrict__ bih1, const float* __restrict__ bhh1,
                                     float* __restrict__ biasg)
{
  int idx = blockIdx.x*256 + threadIdx.x;     // 16 slices * 2 layers * 64
  if (idx >= 16*2*64) return;
  int s = idx >> 7;
  int layer = (idx >> 6) & 1;
  int q = idx & 63;
  int grow = (q >> 4)*256 + s*16 + (q & 15);
  biasg[idx] = layer ? (bih1[grow] + bhh1[grow]) : (bih0[grow] + bhh0[grow]);
}

// ---------------- main persistent kernel: 2 independent groups per block ----------------
extern "C" __global__ void __launch_bounds__(512, 2)
lstm_main(const float* __restrict__ x,
          const uint16_t* __restrict__ wfrag,
          const float* __restrict__ biasg,
          uint16_t* __restrict__ hbase,
          const float* __restrict__ fcw,
          const float* __restrict__ fcb,
          int* __restrict__ flg,    // flags0: 16 groups x 64 ints; flags1: +1024
          float* __restrict__ out)
{
  extern __shared__ uint16_t wlds[];
  __shared__ int scnt[4];            // [grp*2+0]=h0 arrivals, [grp*2+1]=h1 arrivals (monotonic)

  const int tid  = threadIdx.x;
  const int bid  = blockIdx.x;
  const int s    = bid >> 3;         // slice 0..15
  const int gp   = bid & 7;          // group pair 0..7
  const int wv   = tid >> 6;         // wave 0..7
  const int grp  = wv >> 2;          // group-in-block 0..1
  const int wvg  = wv & 3;           // wave-in-group 0..3
  const int g    = gp*2 + grp;       // global group 0..15
  const int lane = tid & 63;

  const int arow = g*64 + wvg*16 + (lane & 15);    // A-frag row
  const int ka   = (lane >> 4) * 8;                // A-frag k base
  const int drow = g*64 + wvg*16 + ((lane >> 4) << 2);
  const int dcol = s*16 + (lane & 15);

  { // stage weight slice (104KB) into LDS (one-time, all 8 waves)
    const uint16_t* wsrc = wfrag + (size_t)s*WSLICE_ELEMS;
    for (int i = tid*8; i < WSLICE_ELEMS; i += 512*8)
      *(short8*)(wlds + i) = *(const short8*)(wsrc + i);
  }
  if (tid < 4) scnt[tid] = 0;
  float b0[4], b1[4];
  {
    const int col = lane & 15;
    #pragma unroll
    for (int n = 0; n < 4; ++n){
      b0[n] = biasg[(s*2+0)*64 + n*16 + col];
      b1[n] = biasg[(s*2+1)*64 + n*16 + col];
    }
  }
  const float fcwv = fcw[dcol];
  const float fcb0 = fcb[0];
  __syncthreads();                   // weights staged + scnt zeroed (pre-loop only)

  const uint16_t* wl = wlds + lane*8;
  const size_t abase = (size_t)arow*256 + ka;
  float c0[4] = {0,0,0,0}, c1[4] = {0,0,0,0};
  int* f0 = flg + g*64;              // flags0[g][0..15], 256B stride per group
  int* f1 = flg + 1024 + g*64;       // flags1[g][0..15]
  int* cnt0 = &scnt[grp*2+0];
  int* cnt1 = &scnt[grp*2+1];

  short8 xh[2], xl[2];
  { // x(0): plain pre-loop loads (compiler-waited)
    const float* xp = x + (size_t)arow*T_STEPS*64 + ka;
    floatx4 v0 = *(const floatx4*)(xp);
    floatx4 v1 = *(const floatx4*)(xp + 4);
    floatx4 v2 = *(const floatx4*)(xp + 32);
    floatx4 v3 = *(const floatx4*)(xp + 36);
    cvt8h(v0, v1, xh[0], xl[0]);
    cvt8h(v2, v3, xh[1], xl[1]);
  }
  short8 k1h[8], k1l[8];             // h1(t-2) frags, held across iterations
  { // pre-loop: h1(-2) = zeros (parity-0 buffers, memset)
    const uint16_t* ph = hbase + 4*(size_t)HN + abase;
    const uint16_t* pl = hbase + 6*(size_t)HN + abase;
    #pragma unroll
    for (int kc = 0; kc < 8; ++kc){
      k1h[kc] = load_coh16(ph + kc*32);
      k1l[kc] = load_coh16(pl + kc*32);
    }
    VM_WAIT(0);
  }

  for (int t = 0; t < T_STEPS; ++t){
    const size_t par0  = (size_t)(t & 1);   // h0(t) write / h1(t-2) read parity
    const size_t rpar0 = par0 ^ 1;          // h0(t-1) read / h1(t-1) write parity

    // ---- poll0: h0(t-1) published by all 16 slices (drains in-flight h1 loads) ----
    poll_flags(f0, t);

    // ---- issue h0(t-1) loads [ops 1-16] + x(t+1) loads [ops 17-20] ----
    short8 a0h[8], a0l[8];
    {
      const uint16_t* ph = hbase + rpar0*HN + abase;
      const uint16_t* pl = hbase + 2*(size_t)HN + rpar0*HN + abase;
      #pragma unroll
      for (int kc = 0; kc < 8; ++kc) a0h[kc] = load_coh16(ph + kc*32);
      #pragma unroll
      for (int kc = 0; kc < 8; ++kc) a0l[kc] = load_coh16(pl + kc*32);
    }
    floatx4 xr0, xr1, xr2, xr3;
    {
      const int tn = (t < T_STEPS-1) ? (t+1) : t;
      const float* xp = x + ((size_t)arow*T_STEPS + tn)*64 + ka;
      xr0 = load_g16f(xp);      xr1 = load_g16f(xp + 4);
      xr2 = load_g16f(xp + 32); xr3 = load_g16f(xp + 36);
    }

    // ---- SHADOW (h0 in flight): W_hh1 x h1(t-2) [64] + x(t) MFMAs [16] ----
    floatx4 acc0[4], acc1[4];
    #pragma unroll
    for (int n = 0; n < 4; ++n){ acc0[n] = splat4(b0[n]); acc1[n] = splat4(b1[n]); }
    #pragma unroll
    for (int kc = 0; kc < 8; ++kc){
      #pragma unroll
      for (int n = 0; n < 4; ++n){
        short8 w = *(const short8*)(wl + L1_OFF + (n*NC1 + 8 + kc)*512);
        acc1[n] = MFMA16(k1h[kc], w, acc1[n]);
        acc1[n] = MFMA16(k1l[kc], w, acc1[n]);
      }
    }
    #pragma unroll
    for (int pk = 0; pk < 2; ++pk){
      #pragma unroll
      for (int n = 0; n < 4; ++n){
        short8 w = *(const short8*)(wl + (n*NC0 + pk)*512);
        acc0[n] = MFMA16(xh[pk], w, acc0[n]);
        acc0[n] = MFMA16(xl[pk], w, acc0[n]);
      }
    }

    VM_WAIT(4);                         // 20 issued - 4 = 16: h0(t-1) in regs

    // ---- shared-A block: L0 W_hh0 + L1 W_ih1 [128 MFMA] ----
    #pragma unroll
    for (int kc = 0; kc < 8; ++kc){
      #pragma unroll
      for (int n = 0; n < 4; ++n){
        short8 w0 = *(const short8*)(wl + (n*NC0 + 2 + kc)*512);
        acc0[n] = MFMA16(a0h[kc], w0, acc0[n]);
        acc0[n] = MFMA16(a0l[kc], w0, acc0[n]);
        short8 w1 = *(const short8*)(wl + L1_OFF + (n*NC1 + kc)*512);
        acc1[n] = MFMA16(a0h[kc], w1, acc1[n]);
        acc1[n] = MFMA16(a0l[kc], w1, acc1[n]);
      }
    }

    // ---- L0 pointwise + publish h0(t): store ops 21-28 ----
    {
      uint16_t* qh = hbase + par0*HN;
      uint16_t* ql = hbase + 2*(size_t)HN + par0*HN;
      #pragma unroll
      for (int r = 0; r < 4; ++r){
        float ig = sigm(acc0[0][r]);
        float fg = sigm(acc0[1][r]);
        float gg = tanhf_(acc0[2][r]);
        float og = sigm(acc0[3][r]);
        c0[r] = fg*c0[r] + ig*gg;
        float h = og*tanhf_(c0[r]);
        _Float16 hh = (_Float16)h;
        _Float16 hl = (_Float16)(h - (float)hh);
        size_t idx = (size_t)(drow + r)*256 + dcol;
        store_coh2(qh + idx, (uint32_t)__builtin_bit_cast(uint16_t, hh));
        store_coh2(ql + idx, (uint32_t)__builtin_bit_cast(uint16_t, hl));
      }
    }
    VM_WAIT(0);                         // x in regs + this wave's h0 stores acked
    // intra-group last-arriver: 4th wave (all stores acked) publishes flag0
    if (lane == 0){
      int old = atomicAdd(cnt0, 1);     // LDS, CU-coherent, monotonic
      if (old == 4*t + 3) flag_store(f0 + s, t+1);
    }

    // ---- shadow tail: x convert, L1 pointwise, h1(t-1) publish ----
    cvt8h(xr0, xr1, xh[0], xl[0]);
    cvt8h(xr2, xr3, xh[1], xl[1]);

    if (t > 0){
      uint16_t* qh = hbase + 4*(size_t)HN + rpar0*HN;
      uint16_t* ql = hbase + 6*(size_t)HN + rpar0*HN;
      #pragma unroll
      for (int r = 0; r < 4; ++r){
        float ig = sigm(acc1[0][r]);
        float fg = sigm(acc1[1][r]);
        float gg = tanhf_(acc1[2][r]);
        float og = sigm(acc1[3][r]);
        c1[r] = fg*c1[r] + ig*gg;
        float h = og*tanhf_(c1[r]);
        _Float16 hh = (_Float16)h;
        _Float16 hl = (_Float16)(h - (float)hh);
        size_t idx = (size_t)(drow + r)*256 + dcol;
        store_coh2(qh + idx, (uint32_t)__builtin_bit_cast(uint16_t, hh));
        store_coh2(ql + idx, (uint32_t)__builtin_bit_cast(uint16_t, hl));
      }
    }
    VM_WAIT(0);                         // h1 stores (+flag0 store) acked
    if (lane == 0){
      int old = atomicAdd(cnt1, 1);
      if (old == 4*t + 3) flag_store(f1 + s, t+1);
    }

    // ---- poll1 (~zero wait: peers just flagged) + issue h1(t-1) loads ----
    poll_flags(f1, t+1);
    {
      const uint16_t* ph = hbase + 4*(size_t)HN + rpar0*HN + abase;
      const uint16_t* pl = hbase + 6*(size_t)HN + rpar0*HN + abase;
      #pragma unroll
      for (int kc = 0; kc < 8; ++kc){
        k1h[kc] = load_coh16(ph + kc*32);   // in flight across the loop edge;
        k1l[kc] = load_coh16(pl + kc*32);   // drained by next poll0
      }
    }
  }

  // ---------------- epilogue: compute L1(511), fused FC via atomicAdd ----------------
  // flags1 >= 512 observed => every producer passed its flag0(512) publish =>
  // h0(511) stores acked at L3. k1 regs = h1(510) (loaded at end of t=511).
  {
    const uint16_t* p0h = hbase + 1*(size_t)HN + abase;   // h0(511) hi, parity 1
    const uint16_t* p0l = hbase + 3*(size_t)HN + abase;   // h0(511) lo
    short8 a0h[8], a0l[8];
    #pragma unroll
    for (int kc = 0; kc < 8; ++kc){
      a0h[kc] = load_coh16(p0h + kc*32);
      a0l[kc] = load_coh16(p0l + kc*32);
    }
    VM_WAIT(0);                        // drains epilogue h0 loads + k1 loads
    floatx4 acc[4];
    #pragma unroll
    for (int n = 0; n < 4; ++n) acc[n] = splat4(b1[n]);
    #pragma unroll
    for (int kc = 0; kc < 8; ++kc){
      #pragma unroll
      for (int n = 0; n < 4; ++n){
        short8 w1 = *(const short8*)(wl + L1_OFF + (n*NC1 + kc)*512);
        acc[n] = MFMA16(a0h[kc], w1, acc[n]);
        acc[n] = MFMA16(a0l[kc], w1, acc[n]);
        short8 w2 = *(const short8*)(wl + L1_OFF + (n*NC1 + 8 + kc)*512);
        acc[n] = MFMA16(k1h[kc], w2, acc[n]);
        acc[n] = MFMA16(k1l[kc], w2, acc[n]);
      }
    }
    #pragma unroll
    for (int r = 0; r < 4; ++r){
      float ig = sigm(acc[0][r]);
      float fg = sigm(acc[1][r]);
      float gg = tanhf_(acc[2][r]);
      float og = sigm(acc[3][r]);
      float cc = fg*c1[r] + ig*gg;
      float h  = og*tanhf_(cc);
      float v  = h * fcwv;
      v += __shfl_xor(v, 1);
      v += __shfl_xor(v, 2);
      v += __shfl_xor(v, 4);
      v += __shfl_xor(v, 8);
      if ((lane & 15) == 0){
        float res = v + ((s == 0) ? fcb0 : 0.0f);
        atomicAdd(out + drow + r, res);
      }
    }
  }
}

// ---------------- host launch ----------------
extern "C" void kernel_launch(void* const* d_in, const int* in_sizes, int n_in,
                              void* d_out, int out_size, void* d_ws, size_t ws_size,
                              hipStream_t stream)
{
  (void)in_sizes; (void)n_in; (void)out_size; (void)ws_size;
  const float* x    = (const float*)d_in[0];
  const float* wih0 = (const float*)d_in[1];
  const float* whh0 = (const float*)d_in[2];
  const float* bih0 = (const float*)d_in[3];
  const float* bhh0 = (const float*)d_in[4];
  const float* wih1 = (const float*)d_in[5];
  const float* whh1 = (const float*)d_in[6];
  const float* bih1 = (const float*)d_in[7];
  const float* bhh1 = (const float*)d_in[8];
  const float* fcw  = (const float*)d_in[9];
  const float* fcb  = (const float*)d_in[10];

  char* ws = (char*)d_ws;
  const size_t SZ_WFRAG = (size_t)16*WSLICE_ELEMS*2;     // 1,703,936
  const size_t OFF_BIAS = SZ_WFRAG;                      // 8KB
  const size_t OFF_FLG  = OFF_BIAS + (size_t)16*2*64*4;  // 2 x 16 x 64 ints = 8KB
  const size_t OFF_H    = (size_t)2*1024*1024;           // h: 8 x 512KB = 4MB

  uint16_t* wfrag = (uint16_t*)(ws);
  float*    biasg = (float*)(ws + OFF_BIAS);
  int*      flg   = (int*)(ws + OFF_FLG);
  uint16_t* hbase = (uint16_t*)(ws + OFF_H);
  float*    out   = (float*)d_out;

  // zero: out (atomicAdd accumulator), flags, h double-buffers
  hipMemsetAsync(d_out, 0, (size_t)1024*sizeof(float), stream);
  hipMemsetAsync(ws + OFF_FLG, 0, (OFF_H - OFF_FLG) + (size_t)8*HN*2, stream);

  hipLaunchKernelGGL(prep_weights, dim3(16*WSLICE_ELEMS/256), dim3(256), 0, stream,
                     wih0, whh0, wih1, whh1, wfrag);
  hipLaunchKernelGGL(prep_bias, dim3(8), dim3(256), 0, stream,
                     bih0, bhh0, bih1, bhh1, biasg);

  hipFuncSetAttribute((const void*)lstm_main,
                      hipFuncAttributeMaxDynamicSharedMemorySize, WSLICE_ELEMS*2);
  void* args[] = { (void*)&x, (void*)&wfrag, (void*)&biasg, (void*)&hbase,
                   (void*)&fcw, (void*)&fcb, (void*)&flg, (void*)&out };
  hipError_t ce = hipLaunchCooperativeKernel((void*)lstm_main, dim3(128), dim3(512),
                                             args, WSLICE_ELEMS*2, stream);
  if (ce != hipSuccess){
    // fallback: plain launch. 104KB dynamic LDS forces 1 block/CU; grid=128 on a
    // 256-CU chip -> all blocks resident, spin polls remain safe.
    hipLaunchKernelGGL(lstm_main, dim3(128), dim3(512), WSLICE_ELEMS*2, stream,
                       x, wfrag, biasg, hbase, fcw, fcb, flg, out);
  }
}

// Round 12
// 4969.697 us; speedup vs baseline: 1.6489x; 1.6489x over previous
//
#include <hip/hip_runtime.h>
#include <stdint.h>

// ---------------- geometry ----------------
// B=1024, T=512, I=64, H=256, gates 4H=1024 (i,f,g,o)
// 256 blocks = 16 slices (s) x 16 groups (g); bid = s*16 + g (R4/R10 block
// structure: 4 waves, wave wv owns rows [g*64+wv*16, +16)).
// slice s owns h-columns [s*16,+16) of BOTH layers.
// R12: SINGLE serialized sync event set per step:
//   one poll + one ack-drain + one __syncthreads + one flag store.
// Single-flag protocol: flag[g][s] = t+1 means "block (s,g) published BOTH
// h0(t) and h1(t-1)". Two-deep h buffers are race-free under one flag:
// a writer of h0(t)/h1(t-1) has passed poll(t) (all peers >= t), and any
// reader of the buffer being overwritten would have to be 2 steps behind,
// which poll(t) excludes (>=-monotone argument).
// Merged loads: after poll, issue h1(t-2)[1-16], h0(t-1)[17-32], x(t+1)
// [33-36]; VM_WAIT(20) gates W_hh1 shadow, VM_WAIT(4) gates shared-A.
// Group phase-stagger (one-time) de-herds the 16 independent groups' L3
// bursts. Exchange data/flags: L3-coherent sc0 sc1 (R4/R10-proven).
// Precision (R7+): weights f16, h hi/lo f16 pair (exact), x hi/lo f16,
// f32 MFMA accum, c state f32 in registers.
// vmcnt ledger per iteration (ALL in-loop vmem inline asm; no runtime-
// indexed local arrays -> no scratch):
//   [enter top: 1 flag store may be outstanding -> poll probes drain to 0]
//   ops 1-16: h1(t-2) loads   ops 17-32: h0(t-1) loads   ops 33-36: x(t+1)
//   VM_WAIT(20) -> h1 in regs;  VM_WAIT(4) -> h0 in regs (x may linger)
//   ops 37-44: h0(t) stores    ops 45-52: h1(t-1) stores (t>0)
//   VM_WAIT(0) -> x in regs + ALL stores acked; __syncthreads; tid0 flag.

#define T_STEPS 512
#define NC0 10
#define NC1 16
#define WSLICE_ELEMS (4*(NC0+NC1)*512)   // 53248 f16 elems = 104KB
#define L1_OFF (4*NC0*512)               // 20480
#define HN (1024*256)                    // elems per h array
// h layout: h0hi[p]=hbase+p*HN, h0lo[p]=+2HN+p*HN, h1hi[p]=+4HN+p*HN, h1lo[p]=+6HN+p*HN

typedef __attribute__((ext_vector_type(8))) short short8;
typedef __attribute__((ext_vector_type(4))) float floatx4;
typedef __attribute__((ext_vector_type(4))) int   intx4;
typedef _Float16 half8 __attribute__((ext_vector_type(8)));

#define MFMA16(A,B,C) __builtin_amdgcn_mfma_f32_16x16x32_f16( \
    __builtin_bit_cast(half8,(A)), __builtin_bit_cast(half8,(B)), (C), 0, 0, 0)

__device__ __forceinline__ float sigm(float x){
  return __builtin_amdgcn_rcpf(1.0f + __builtin_amdgcn_exp2f(-1.44269504f*x));
}
__device__ __forceinline__ float tanhf_(float x){
  return 1.0f - 2.0f*__builtin_amdgcn_rcpf(1.0f + __builtin_amdgcn_exp2f(2.88539008f*x));
}
__device__ __forceinline__ floatx4 splat4(float v){ return (floatx4){v,v,v,v}; }
__device__ __forceinline__ int imin2(int a, int b){ return a < b ? a : b; }

__device__ __forceinline__ void cvt8h(const floatx4& v0, const floatx4& v1, short8& hi, short8& lo){
  #pragma unroll
  for (int j = 0; j < 8; ++j){
    float f = (j < 4) ? v0[j] : v1[j-4];
    _Float16 h = (_Float16)f;
    _Float16 l = (_Float16)(f - (float)h);
    hi[j] = (short)__builtin_bit_cast(uint16_t, h);
    lo[j] = (short)__builtin_bit_cast(uint16_t, l);
  }
}

// ---- L3-coherent vmem (sc0 sc1) ----
__device__ __forceinline__ short8 load_coh16(const uint16_t* p){
  short8 r;
  asm volatile("global_load_dwordx4 %0, %1, off sc0 sc1" : "=v"(r) : "v"(p));
  return r;
}
__device__ __forceinline__ void store_coh2(uint16_t* p, uint32_t v){
  asm volatile("global_store_short %0, %1, off sc0 sc1" :: "v"(p), "v"(v) : "memory");
}
__device__ __forceinline__ floatx4 load_g16f(const float* p){
  floatx4 r;
  asm volatile("global_load_dwordx4 %0, %1, off" : "=v"(r) : "v"(p));
  return r;
}
__device__ __forceinline__ void flag_store(int* p, int v){
  asm volatile("global_store_dword %0, %1, off sc0 sc1" :: "v"(p), "v"(v) : "memory");
}
__device__ __forceinline__ intx4 load_flags4(const int* p){
  intx4 r;
  asm volatile("global_load_dwordx4 %0, %1, off sc0 sc1" : "=v"(r) : "v"(p));
  return r;
}
#define VM_WAIT(N) do{ asm volatile("s_waitcnt vmcnt(" #N ")" ::: "memory"); \
                       __builtin_amdgcn_sched_barrier(0); }while(0)

// Poll 16 contiguous flag words until min >= target (wave-uniform broadcast
// loads). Every probe drains vmcnt(0) -> any in-flight ops from the previous
// phase (incl. our own last flag store) are drained on exit.
__device__ __forceinline__ void poll_flags(const int* f, int target){
  int spins = 0;
  for(;;){
    intx4 a = load_flags4(f);
    intx4 b = load_flags4(f + 4);
    intx4 c = load_flags4(f + 8);
    intx4 d = load_flags4(f + 12);
    VM_WAIT(0);
    int m = imin2(imin2(a[0],a[1]), imin2(a[2],a[3]));
    m = imin2(m, imin2(imin2(b[0],b[1]), imin2(b[2],b[3])));
    m = imin2(m, imin2(imin2(c[0],c[1]), imin2(c[2],c[3])));
    m = imin2(m, imin2(imin2(d[0],d[1]), imin2(d[2],d[3])));
    if (m >= target) break;
    if (++spins > (1<<20)) break;      // bounded: fail loud, never hang
    __builtin_amdgcn_s_sleep(1);
  }
  __builtin_amdgcn_sched_barrier(0);   // keep consumers below the final wait
}

// ---------------- prep: gather weights into per-slice B-fragment images (f16) ----------------
extern "C" __global__ void prep_weights(const float* __restrict__ wih0, const float* __restrict__ whh0,
                                        const float* __restrict__ wih1, const float* __restrict__ whh1,
                                        uint16_t* __restrict__ wfrag)
{
  int idx = blockIdx.x*256 + threadIdx.x;     // exactly 16*WSLICE_ELEMS threads
  int s  = idx / WSLICE_ELEMS;
  int r  = idx - s*WSLICE_ELEMS;
  int layer = (r >= L1_OFF) ? 1 : 0;
  int rr = layer ? (r - L1_OFF) : r;
  int nc = layer ? NC1 : NC0;
  int n  = rr / (nc*512);
  int c  = (rr / 512) % nc;
  int l  = (rr >> 3) & 63;
  int j  = rr & 7;
  int k  = c*32 + ((l >> 4) << 3) + j;        // B frag: lane l holds col=l&15, k=8*(l>>4)+j
  int grow = n*256 + s*16 + (l & 15);
  float v;
  if (!layer) v = (k < 64)  ? wih0[grow*64  + k] : whh0[grow*256 + (k - 64)];
  else        v = (k < 256) ? wih1[grow*256 + k] : whh1[grow*256 + (k - 256)];
  wfrag[idx] = __builtin_bit_cast(uint16_t, (_Float16)v);
}

extern "C" __global__ void prep_bias(const float* __restrict__ bih0, const float* __restrict__ bhh0,
                                     const float* __restrict__ bih1, const float* __restrict__ bhh1,
                                     float* __restrict__ biasg)
{
  int idx = blockIdx.x*256 + threadIdx.x;     // 16 slices * 2 layers * 64
  if (idx >= 16*2*64) return;
  int s = idx >> 7;
  int layer = (idx >> 6) & 1;
  int q = idx & 63;
  int grow = (q >> 4)*256 + s*16 + (q & 15);
  biasg[idx] = layer ? (bih1[grow] + bhh1[grow]) : (bih0[grow] + bhh0[grow]);
}

// ---------------- main persistent kernel ----------------
extern "C" __global__ void __launch_bounds__(256, 1)
lstm_main(const float* __restrict__ x,
          const uint16_t* __restrict__ wfrag,
          const float* __restrict__ biasg,
          uint16_t* __restrict__ hbase,
          const float* __restrict__ fcw,
          const float* __restrict__ fcb,
          int* __restrict__ flg,    // 16 groups x 64 ints (one flag line/group)
          float* __restrict__ out)
{
  extern __shared__ uint16_t wlds[];
  const int tid  = threadIdx.x;
  const int bid  = blockIdx.x;
  const int s    = bid >> 4;         // slice
  const int g    = bid & 15;         // group (64 batch rows)
  const int wv   = tid >> 6;
  const int lane = tid & 63;

  const int arow = g*64 + wv*16 + (lane & 15);     // A-frag row
  const int ka   = (lane >> 4) * 8;                // A-frag k base
  const int drow = g*64 + wv*16 + ((lane >> 4) << 2);
  const int dcol = s*16 + (lane & 15);

  { // stage weight slice (104KB) into LDS (one-time, all 4 waves)
    const uint16_t* wsrc = wfrag + (size_t)s*WSLICE_ELEMS;
    for (int i = tid*8; i < WSLICE_ELEMS; i += 256*8)
      *(short8*)(wlds + i) = *(const short8*)(wsrc + i);
  }
  float b0[4], b1[4];
  {
    const int col = lane & 15;
    #pragma unroll
    for (int n = 0; n < 4; ++n){
      b0[n] = biasg[(s*2+0)*64 + n*16 + col];
      b1[n] = biasg[(s*2+1)*64 + n*16 + col];
    }
  }
  const float fcwv = fcw[dcol];
  const float fcb0 = fcb[0];
  __syncthreads();                   // weights staged

  const uint16_t* wl = wlds + lane*8;
  const size_t abase = (size_t)arow*256 + ka;
  float c0[4] = {0,0,0,0}, c1[4] = {0,0,0,0};
  int* f0 = flg + g*64;              // flags[g][0..15], 256B stride per group

  short8 xh[2], xl[2];
  { // x(0): plain pre-loop loads (compiler-waited)
    const float* xp = x + (size_t)arow*T_STEPS*64 + ka;
    floatx4 v0 = *(const floatx4*)(xp);
    floatx4 v1 = *(const floatx4*)(xp + 4);
    floatx4 v2 = *(const floatx4*)(xp + 32);
    floatx4 v3 = *(const floatx4*)(xp + 36);
    cvt8h(v0, v1, xh[0], xl[0]);
    cvt8h(v2, v3, xh[1], xl[1]);
  }

  // one-time group phase-stagger: spread the 16 independent groups' L3
  // bursts (~0.3us per g); groups are uncoupled so offsets persist.
  for (int i = 0; i < g*6; ++i) __builtin_amdgcn_s_sleep(2);

  for (int t = 0; t < T_STEPS; ++t){
    const size_t par0  = (size_t)(t & 1);   // h0(t) write / h1(t-2) read parity
    const size_t rpar0 = par0 ^ 1;          // h0(t-1) read / h1(t-1) write parity

    // ---- ONE poll: flag >= t covers h0(t-1) AND h1(t-2) ----
    poll_flags(f0, t);

    // ---- merged issue: h1(t-2) [1-16], h0(t-1) [17-32], x(t+1) [33-36] ----
    short8 a1h[8], a1l[8], a0h[8], a0l[8];
    {
      const uint16_t* ph = hbase + 4*(size_t)HN + par0*HN + abase;
      const uint16_t* pl = hbase + 6*(size_t)HN + par0*HN + abase;
      #pragma unroll
      for (int kc = 0; kc < 8; ++kc) a1h[kc] = load_coh16(ph + kc*32);
      #pragma unroll
      for (int kc = 0; kc < 8; ++kc) a1l[kc] = load_coh16(pl + kc*32);
    }
    {
      const uint16_t* ph = hbase + rpar0*HN + abase;
      const uint16_t* pl = hbase + 2*(size_t)HN + rpar0*HN + abase;
      #pragma unroll
      for (int kc = 0; kc < 8; ++kc) a0h[kc] = load_coh16(ph + kc*32);
      #pragma unroll
      for (int kc = 0; kc < 8; ++kc) a0l[kc] = load_coh16(pl + kc*32);
    }
    floatx4 xr0, xr1, xr2, xr3;
    {
      const int tn = (t < T_STEPS-1) ? (t+1) : t;
      const float* xp = x + ((size_t)arow*T_STEPS + tn)*64 + ka;
      xr0 = load_g16f(xp);      xr1 = load_g16f(xp + 4);
      xr2 = load_g16f(xp + 32); xr3 = load_g16f(xp + 36);
    }

    // ---- x(t) MFMAs (operands in regs) while everything flies ----
    floatx4 acc0[4], acc1[4];
    #pragma unroll
    for (int n = 0; n < 4; ++n){ acc0[n] = splat4(b0[n]); acc1[n] = splat4(b1[n]); }
    #pragma unroll
    for (int pk = 0; pk < 2; ++pk){
      #pragma unroll
      for (int n = 0; n < 4; ++n){
        short8 w = *(const short8*)(wl + (n*NC0 + pk)*512);
        acc0[n] = MFMA16(xh[pk], w, acc0[n]);
        acc0[n] = MFMA16(xl[pk], w, acc0[n]);
      }
    }

    VM_WAIT(20);                        // 36 - 20 = 16: h1(t-2) in regs

    // ---- W_hh1 x h1(t-2) [64 MFMA] shadows the h0 flight ----
    #pragma unroll
    for (int kc = 0; kc < 8; ++kc){
      #pragma unroll
      for (int n = 0; n < 4; ++n){
        short8 w = *(const short8*)(wl + L1_OFF + (n*NC1 + 8 + kc)*512);
        acc1[n] = MFMA16(a1h[kc], w, acc1[n]);
        acc1[n] = MFMA16(a1l[kc], w, acc1[n]);
      }
    }

    VM_WAIT(4);                         // 36 - 4 = 32: h0(t-1) in regs (x may linger)

    // ---- shared-A block: L0 W_hh0 + L1 W_ih1 [128 MFMA] ----
    #pragma unroll
    for (int kc = 0; kc < 8; ++kc){
      #pragma unroll
      for (int n = 0; n < 4; ++n){
        short8 w0 = *(const short8*)(wl + (n*NC0 + 2 + kc)*512);
        acc0[n] = MFMA16(a0h[kc], w0, acc0[n]);
        acc0[n] = MFMA16(a0l[kc], w0, acc0[n]);
        short8 w1 = *(const short8*)(wl + L1_OFF + (n*NC1 + kc)*512);
        acc1[n] = MFMA16(a0h[kc], w1, acc1[n]);
        acc1[n] = MFMA16(a0l[kc], w1, acc1[n]);
      }
    }

    // ---- L0 pointwise + h0(t) stores [37-44] ----
    {
      uint16_t* qh = hbase + par0*HN;
      uint16_t* ql = hbase + 2*(size_t)HN + par0*HN;
      #pragma unroll
      for (int r = 0; r < 4; ++r){
        float ig = sigm(acc0[0][r]);
        float fg = sigm(acc0[1][r]);
        float gg = tanhf_(acc0[2][r]);
        float og = sigm(acc0[3][r]);
        c0[r] = fg*c0[r] + ig*gg;
        float h = og*tanhf_(c0[r]);
        _Float16 hh = (_Float16)h;
        _Float16 hl = (_Float16)(h - (float)hh);
        size_t idx = (size_t)(drow + r)*256 + dcol;
        store_coh2(qh + idx, (uint32_t)__builtin_bit_cast(uint16_t, hh));
        store_coh2(ql + idx, (uint32_t)__builtin_bit_cast(uint16_t, hl));
      }
    }
    // ---- L1 pointwise + h1(t-1) stores [45-52] (skipped at t=0) ----
    if (t > 0){
      uint16_t* qh = hbase + 4*(size_t)HN + rpar0*HN;
      uint16_t* ql = hbase + 6*(size_t)HN + rpar0*HN;
      #pragma unroll
      for (int r = 0; r < 4; ++r){
        float ig = sigm(acc1[0][r]);
        float fg = sigm(acc1[1][r]);
        float gg = tanhf_(acc1[2][r]);
        float og = sigm(acc1[3][r]);
        c1[r] = fg*c1[r] + ig*gg;
        float h = og*tanhf_(c1[r]);
        _Float16 hh = (_Float16)h;
        _Float16 hl = (_Float16)(h - (float)hh);
        size_t idx = (size_t)(drow + r)*256 + dcol;
        store_coh2(qh + idx, (uint32_t)__builtin_bit_cast(uint16_t, hh));
        store_coh2(ql + idx, (uint32_t)__builtin_bit_cast(uint16_t, hl));
      }
    }

    VM_WAIT(0);                         // x in regs + ALL h stores acked at L3
    __syncthreads();                    // all 4 waves' stores acked
    if (tid == 0) flag_store(f0 + s, t+1);   // ONE flag: h0(t) + h1(t-1) published
    // flag store left in flight; next poll's probes drain it.

    // x(t+1) convert (off the publish path)
    cvt8h(xr0, xr1, xh[0], xl[0]);
    cvt8h(xr2, xr3, xh[1], xl[1]);
  }

  // ---------------- epilogue: compute L1(511), fused FC via atomicAdd ----------------
  poll_flags(f0, T_STEPS);             // h0(511) + h1(510) published by all peers
  {
    const uint16_t* p0h = hbase + 1*(size_t)HN + abase;   // h0(511) hi, parity 1
    const uint16_t* p0l = hbase + 3*(size_t)HN + abase;   // h0(511) lo
    const uint16_t* p1h = hbase + 4*(size_t)HN + abase;   // h1(510) hi, parity 0
    const uint16_t* p1l = hbase + 6*(size_t)HN + abase;   // h1(510) lo
    short8 a0h[8], a0l[8], a1h[8], a1l[8];
    #pragma unroll
    for (int kc = 0; kc < 8; ++kc){
      a0h[kc] = load_coh16(p0h + kc*32);
      a0l[kc] = load_coh16(p0l + kc*32);
      a1h[kc] = load_coh16(p1h + kc*32);
      a1l[kc] = load_coh16(p1l + kc*32);
    }
    VM_WAIT(0);
    floatx4 acc[4];
    #pragma unroll
    for (int n = 0; n < 4; ++n) acc[n] = splat4(b1[n]);
    #pragma unroll
    for (int kc = 0; kc < 8; ++kc){
      #pragma unroll
      for (int n = 0; n < 4; ++n){
        short8 w1 = *(const short8*)(wl + L1_OFF + (n*NC1 + kc)*512);
        acc[n] = MFMA16(a0h[kc], w1, acc[n]);
        acc[n] = MFMA16(a0l[kc], w1, acc[n]);
        short8 w2 = *(const short8*)(wl + L1_OFF + (n*NC1 + 8 + kc)*512);
        acc[n] = MFMA16(a1h[kc], w2, acc[n]);
        acc[n] = MFMA16(a1l[kc], w2, acc[n]);
      }
    }
    #pragma unroll
    for (int r = 0; r < 4; ++r){
      float ig = sigm(acc[0][r]);
      float fg = sigm(acc[1][r]);
      float gg = tanhf_(acc[2][r]);
      float og = sigm(acc[3][r]);
      float cc = fg*c1[r] + ig*gg;
      float h  = og*tanhf_(cc);
      float v  = h * fcwv;
      v += __shfl_xor(v, 1);
      v += __shfl_xor(v, 2);
      v += __shfl_xor(v, 4);
      v += __shfl_xor(v, 8);
      if ((lane & 15) == 0){
        float res = v + ((s == 0) ? fcb0 : 0.0f);
        atomicAdd(out + drow + r, res);
      }
    }
  }
}

// ---------------- host launch ----------------
extern "C" void kernel_launch(void* const* d_in, const int* in_sizes, int n_in,
                              void* d_out, int out_size, void* d_ws, size_t ws_size,
                              hipStream_t stream)
{
  (void)in_sizes; (void)n_in; (void)out_size; (void)ws_size;
  const float* x    = (const float*)d_in[0];
  const float* wih0 = (const float*)d_in[1];
  const float* whh0 = (const float*)d_in[2];
  const float* bih0 = (const float*)d_in[3];
  const float* bhh0 = (const float*)d_in[4];
  const float* wih1 = (const float*)d_in[5];
  const float* whh1 = (const float*)d_in[6];
  const float* bih1 = (const float*)d_in[7];
  const float* bhh1 = (const float*)d_in[8];
  const float* fcw  = (const float*)d_in[9];
  const float* fcb  = (const float*)d_in[10];

  char* ws = (char*)d_ws;
  const size_t SZ_WFRAG = (size_t)16*WSLICE_ELEMS*2;     // 1,703,936
  const size_t OFF_BIAS = SZ_WFRAG;                      // 8KB
  const size_t OFF_FLG  = OFF_BIAS + (size_t)16*2*64*4;  // 16 x 64 ints = 4KB
  const size_t OFF_H    = (size_t)2*1024*1024;           // h: 8 x 512KB = 4MB

  uint16_t* wfrag = (uint16_t*)(ws);
  float*    biasg = (float*)(ws + OFF_BIAS);
  int*      flg   = (int*)(ws + OFF_FLG);
  uint16_t* hbase = (uint16_t*)(ws + OFF_H);
  float*    out   = (float*)d_out;

  // zero: out (atomicAdd accumulator), flags, h double-buffers
  hipMemsetAsync(d_out, 0, (size_t)1024*sizeof(float), stream);
  hipMemsetAsync(ws + OFF_FLG, 0, (OFF_H - OFF_FLG) + (size_t)8*HN*2, stream);

  hipLaunchKernelGGL(prep_weights, dim3(16*WSLICE_ELEMS/256), dim3(256), 0, stream,
                     wih0, whh0, wih1, whh1, wfrag);
  hipLaunchKernelGGL(prep_bias, dim3(8), dim3(256), 0, stream,
                     bih0, bhh0, bih1, bhh1, biasg);

  hipFuncSetAttribute((const void*)lstm_main,
                      hipFuncAttributeMaxDynamicSharedMemorySize, WSLICE_ELEMS*2);
  void* args[] = { (void*)&x, (void*)&wfrag, (void*)&biasg, (void*)&hbase,
                   (void*)&fcw, (void*)&fcb, (void*)&flg, (void*)&out };
  hipError_t ce = hipLaunchCooperativeKernel((void*)lstm_main, dim3(256), dim3(256),
                                             args, WSLICE_ELEMS*2, stream);
  if (ce != hipSuccess){
    // fallback: plain launch. 104KB dynamic LDS forces 1 block/CU; grid=256 on a
    // 256-CU chip -> all blocks resident, spin polls remain safe.
    hipLaunchKernelGGL(lstm_main, dim3(256), dim3(256), WSLICE_ELEMS*2, stream,
                       x, wfrag, biasg, hbase, fcw, fcb, flg, out);
  }
}